// Round 4
// baseline (478.907 us; speedup 1.0000x reference)
//
#include <hip/hip_runtime.h>
#include <hip/hip_bf16.h>

typedef __bf16 bf16_t;
typedef __bf16 bf16x8 __attribute__((ext_vector_type(8)));
typedef float  f32x4  __attribute__((ext_vector_type(4)));

static __device__ __forceinline__ f32x4 mfma16(bf16x8 a, bf16x8 b, f32x4 c) {
    return __builtin_amdgcn_mfma_f32_16x16x32_bf16(a, b, c, 0, 0, 0);
}
static __device__ __forceinline__ float fast_rcp(float x) {
    return __builtin_amdgcn_rcpf(x);
}
static __device__ __forceinline__ void nt_store(float v, float* p) {
    __builtin_nontemporal_store(v, p);
}

// ws fragment-layout weight offsets (bf16 elements). Fragment block = 512
// elems = (64 lanes x 8 elems); block index = tile*frags + f.
#define OFF_W10 0
#define OFF_W11 86016
#define OFF_W12 98304
#define OFF_W20 101376
#define OFF_W21 150528
#define OFF_W22 162816
#define W_TOTAL 165888

// Coalesced-read weight prep: thread idx walks the SOURCE linearly,
// destination computed by inverting the fragment layout.
template<int K, int N, int OFF>
static __device__ __forceinline__ void scatter_seg(const float* __restrict__ src,
                                                   bf16_t* __restrict__ ws, int local) {
    int k  = local / N;            // constant N -> magic-mul
    int n  = local - k * N;
    int f  = k >> 5;
    int kr = k & 31;
    int lane = ((kr >> 3) << 4) | (n & 15);
    int dst  = OFF + ((((n >> 4) * (K >> 5)) + f) << 9) + (lane << 3) + (kr & 7);
    ws[dst] = (bf16_t)src[local];
}

__global__ void prep_weights(const float* __restrict__ W10, const float* __restrict__ W11,
                             const float* __restrict__ W12, const float* __restrict__ W20,
                             const float* __restrict__ W21, const float* __restrict__ W22,
                             bf16_t* __restrict__ ws) {
    int idx = blockIdx.x * 256 + threadIdx.x;
    if (idx >= W_TOTAL) return;
    if      (idx < OFF_W11) scatter_seg<128, 672, OFF_W10>(W10, ws, idx - OFF_W10);
    else if (idx < OFF_W12) scatter_seg< 64, 192, OFF_W11>(W11, ws, idx - OFF_W11);
    else if (idx < OFF_W20) scatter_seg< 32,  96, OFF_W12>(W12, ws, idx - OFF_W12);
    else if (idx < OFF_W21) scatter_seg<384, 128, OFF_W20>(W20, ws, idx - OFF_W20);
    else if (idx < OFF_W22) scatter_seg<192,  64, OFF_W21>(W21, ws, idx - OFF_W21);
    else                    scatter_seg< 96,  32, OFF_W22>(W22, ws, idx - OFF_W22);
}

// LDS plan (bf16 elems in smid, total 17920 = 35840 B):
//   [0,9600)     : xde (7808 used) during S0/S1, then mid1 (3 planes x 3200) in S2
//   [9600,17920) : mid0 (6272 used) in S1/S2, then mid2 (5 planes x 1664) in S3
// Gates live in REGISTERS (producer tile 24+t and consumer tile t are the same
// wave and same lane). Biases staged in LDS (sb1/sb2, 3.2 KB). Total LDS
// 39104 B -> 4 blocks/CU. Output written with NON-TEMPORAL stores: out is
// write-once, and keeping it out of L2 stops dirty-line thrash between the
// three barrier-separated epilogue phases (round-3 WRITE_SIZE was 312 MB vs
// a 192 MB output).
#define XDE_S   488
#define MID0_S  392
#define MID1_S  200
#define MID2_S  104
#define MID0_B  9600
#define MID2_B  9600

__global__ __launch_bounds__(256, 4)
void ffn_kernel(const float* __restrict__ x, const float* __restrict__ attr,
                const float* __restrict__ b1, const float* __restrict__ b2,
                const bf16_t* __restrict__ wf, float* __restrict__ out) {
    __shared__ bf16_t smid[17920];
    __shared__ float  sattr[16];
    __shared__ float  sb1[672];
    __shared__ float  sb2[128];

    const int tid   = threadIdx.x;
    const int lane  = tid & 63;
    const int w     = tid >> 6;
    const int rlane = lane & 15;
    const int q     = lane >> 4;
    const int rowbase = blockIdx.x * 16;

    // ---------------- S0: stage x (de-interleaved bf16), biases, attr ----
    for (int it = 0; it < 8; ++it) {
        int idx = tid + it * 256;
        if (idx < 1920) {
            int row = idx / 120;
            int c4  = idx - row * 120;
            const float4 v = ((const float4*)(x + (size_t)(rowbase + row) * 480))[c4];
            float vals[4] = {v.x, v.y, v.z, v.w};
            int base = c4 * 4;
#pragma unroll
            for (int e = 0; e < 4; ++e) {
                int col = base + e;
                int dc;
                if (col < 128) dc = col;
                else if (col < 320) { int r = col - 128; int m = r / 3; int i = r - m * 3; dc = 128 + i * 64 + m; }
                else                { int r = col - 320; int m = r / 5; int i = r - m * 5; dc = 320 + i * 32 + m; }
                smid[row * XDE_S + dc] = (bf16_t)vals[e];
            }
        }
    }
    for (int i = tid; i < 672; i += 256) sb1[i] = b1[i];
    if (tid < 128) sb2[tid] = b2[tid];
    if (tid < 16)  sattr[tid] = attr[rowbase + tid];
    __syncthreads();                                   // B1

    // per-wave attr registers (row = q*4 + r)
    float sat[4];
#pragma unroll
    for (int r = 0; r < 4; ++r) sat[r] = sattr[q * 4 + r];

    // ---------------- extract A fragments --------------------------------
    bf16x8 a0[4], a1[3][2], a2[5];
    {
        int rb = rlane * XDE_S + q * 8;
#pragma unroll
        for (int f = 0; f < 4; ++f) a0[f] = *(const bf16x8*)&smid[rb + f * 32];
#pragma unroll
        for (int i = 0; i < 3; ++i)
#pragma unroll
            for (int f = 0; f < 2; ++f) a1[i][f] = *(const bf16x8*)&smid[rb + 128 + i * 64 + f * 32];
#pragma unroll
        for (int i = 0; i < 5; ++i) a2[i] = *(const bf16x8*)&smid[rb + 320 + i * 32];
    }

    // sigmoid gates, register-resident, statically indexed (loop fully
    // unrolled so gv[ti-6] is compile-time). gv[k] <- P1l0 tile 24+w+4k;
    // consumed by P1l1 (gv[0..2]) and P1l2 (gv[3..4]). Waves 2,3 use gv[0..3].
    float gv[5][4];

    // ---------------- S1: P1l0, software-pipelined weight prefetch --------
    {
        const float inv = 0.088388347648318447f;       // 1/sqrt(128)
        const bf16_t* base10 = wf + OFF_W10 + (lane << 3);
        bf16x8 bc[4];
        {
            const bf16_t* p = base10 + ((w * 4) << 9);
#pragma unroll
            for (int f = 0; f < 4; ++f) bc[f] = *(const bf16x8*)(p + (f << 9));
        }
#pragma unroll
        for (int ti = 0; ti < 11; ++ti) {
            int t  = w + ti * 4;
            int tn = t + 4;
            bf16x8 bn[4] = {bc[0], bc[1], bc[2], bc[3]};
            if (ti < 10 && tn < 42) {                  // prefetch next tile
                const bf16_t* p = base10 + ((tn * 4) << 9);
#pragma unroll
                for (int f = 0; f < 4; ++f) bn[f] = *(const bf16x8*)(p + (f << 9));
            }
            if (t < 42) {                              // ti==10 only for w<2
                f32x4 acc = {0.f, 0.f, 0.f, 0.f};
#pragma unroll
                for (int f = 0; f < 4; ++f) acc = mfma16(a0[f], bc[f], acc);
                int c = t * 16 + rlane;
                float bias = sb1[c];
                if (ti < 6) {                          // t<24: scalars -> silu -> mid0
#pragma unroll
                    for (int r = 0; r < 4; ++r) {
                        float v = acc[r] * inv * sat[r] + bias;
                        float s = v * fast_rcp(1.f + __expf(-v));
                        smid[MID0_B + (q * 4 + r) * MID0_S + c] = (bf16_t)s;
                    }
                } else {                               // gates -> sigmoid -> regs
#pragma unroll
                    for (int r = 0; r < 4; ++r) {
                        float v = acc[r] * inv * sat[r] + bias;
                        gv[ti - 6][r] = fast_rcp(1.f + __expf(-v));
                    }
                }
            }
#pragma unroll
            for (int f = 0; f < 4; ++f) bc[f] = bn[f];
        }
    }
    __syncthreads();                                   // B2

    // ---------------- S2: P2l0 (out cols 0..127) + P1l1 (mid1) -----------
    {
        const float inv = 0.051031036307982884f;       // 1/sqrt(384)
        bf16x8 am[12];
        int rb = MID0_B + rlane * MID0_S + q * 8;
#pragma unroll
        for (int f = 0; f < 12; ++f) am[f] = *(const bf16x8*)&smid[rb + f * 32];
#pragma unroll
        for (int ti = 0; ti < 2; ++ti) {
            int t = w + ti * 4;
            const bf16_t* p = wf + OFF_W20 + ((t * 12) << 9) + (lane << 3);
            float bias = sb2[t * 16 + rlane];
            f32x4 acc = {0.f, 0.f, 0.f, 0.f};
#pragma unroll
            for (int f = 0; f < 12; ++f)
                acc = mfma16(am[f], *(const bf16x8*)(p + (f << 9)), acc);
            int c = t * 16 + rlane;
#pragma unroll
            for (int r = 0; r < 4; ++r)
                nt_store(acc[r] * inv * sat[r] + bias,
                         out + (size_t)(rowbase + q * 4 + r) * 480 + c);
        }
    }
    {
        const float inv = 0.125f;                      // 1/sqrt(64)
#pragma unroll
        for (int ti = 0; ti < 3; ++ti) {
            int t = w + ti * 4;
            const bf16_t* p = wf + OFF_W11 + ((t * 2) << 9) + (lane << 3);
            bf16x8 b0  = *(const bf16x8*)p;
            bf16x8 b1f = *(const bf16x8*)(p + 512);
            f32x4 acc[3];
#pragma unroll
            for (int i = 0; i < 3; ++i) {
                f32x4 a = {0.f, 0.f, 0.f, 0.f};
                a = mfma16(a1[i][0], b0, a);
                a = mfma16(a1[i][1], b1f, a);
                acc[i] = a;
            }
            int m = t * 16 + rlane;
#pragma unroll
            for (int r = 0; r < 4; ++r) {
                int row = q * 4 + r;
                float g = gv[ti][r] * inv * sat[r];
#pragma unroll
                for (int i = 0; i < 3; ++i)
                    smid[i * 3200 + row * MID1_S + m] = (bf16_t)(acc[i][r] * g);
            }
        }
    }
    __syncthreads();                                   // B3

    // ---------------- S3: P1l2 (mid2) + P2l1 (out cols 128..319) ---------
    {
        const float inv = 0.17677669529663689f;        // 1/sqrt(32)
#pragma unroll
        for (int ti = 0; ti < 2; ++ti) {
            int t = w + ti * 4;
            if (ti == 1 && t >= 6) continue;           // waves 2,3: single tile
            const bf16_t* p = wf + OFF_W12 + (t << 9) + (lane << 3);
            bf16x8 b = *(const bf16x8*)p;
            f32x4 acc[5];
#pragma unroll
            for (int i = 0; i < 5; ++i) {
                f32x4 a = {0.f, 0.f, 0.f, 0.f};
                acc[i] = mfma16(a2[i], b, a);
            }
            int m = t * 16 + rlane;
#pragma unroll
            for (int r = 0; r < 4; ++r) {
                int row = q * 4 + r;
                float g = gv[3 + ti][r] * inv * sat[r];
#pragma unroll
                for (int i = 0; i < 5; ++i)
                    smid[MID2_B + i * 1664 + row * MID2_S + m] = (bf16_t)(acc[i][r] * g);
            }
        }
    }
    {
        const float inv = 0.072168783648703220f;       // 1/sqrt(192)
        int t = w;                                     // 4 tiles exactly
        const bf16_t* p = wf + OFF_W21 + ((t * 6) << 9) + (lane << 3);
        bf16x8 b[6];
#pragma unroll
        for (int f = 0; f < 6; ++f) b[f] = *(const bf16x8*)(p + (f << 9));
        f32x4 acc[3];
#pragma unroll
        for (int i = 0; i < 3; ++i) {
            bf16x8 am[6];
            int rb = i * 3200 + rlane * MID1_S + q * 8;
#pragma unroll
            for (int f = 0; f < 6; ++f) am[f] = *(const bf16x8*)&smid[rb + f * 32];
            f32x4 a = {0.f, 0.f, 0.f, 0.f};
#pragma unroll
            for (int f = 0; f < 6; ++f) a = mfma16(am[f], b[f], a);
            acc[i] = a;
        }
        int o = t * 16 + rlane;
#pragma unroll
        for (int r = 0; r < 4; ++r) {
            float s = inv * sat[r];
            float* dst = out + (size_t)(rowbase + q * 4 + r) * 480 + 128 + o * 3;
            nt_store(acc[0][r] * s, dst + 0);
            nt_store(acc[1][r] * s, dst + 1);
            nt_store(acc[2][r] * s, dst + 2);
        }
    }
    __syncthreads();                                   // B4

    // ---------------- S4: P2l2 (out cols 320..479) -----------------------
    if (w < 2) {
        const float inv = 0.10206207261596575f;        // 1/sqrt(96)
        int t = w;                                     // 2 tiles
        const bf16_t* p = wf + OFF_W22 + ((t * 3) << 9) + (lane << 3);
        bf16x8 b[3];
#pragma unroll
        for (int f = 0; f < 3; ++f) b[f] = *(const bf16x8*)(p + (f << 9));
        f32x4 acc[5];
#pragma unroll
        for (int i = 0; i < 5; ++i) {
            bf16x8 am[3];
            int rb = MID2_B + i * 1664 + rlane * MID2_S + q * 8;
#pragma unroll
            for (int f = 0; f < 3; ++f) am[f] = *(const bf16x8*)&smid[rb + f * 32];
            f32x4 a = {0.f, 0.f, 0.f, 0.f};
#pragma unroll
            for (int f = 0; f < 3; ++f) a = mfma16(am[f], b[f], a);
            acc[i] = a;
        }
        int o = t * 16 + rlane;
#pragma unroll
        for (int r = 0; r < 4; ++r) {
            float s = inv * sat[r];
            float* dst = out + (size_t)(rowbase + q * 4 + r) * 480 + 320 + o * 5;
#pragma unroll
            for (int i = 0; i < 5; ++i) nt_store(acc[i][r] * s, dst + i);
        }
    }
}

extern "C" void kernel_launch(void* const* d_in, const int* in_sizes, int n_in,
                              void* d_out, int out_size, void* d_ws, size_t ws_size,
                              hipStream_t stream) {
    const float* x    = (const float*)d_in[0];
    const float* attr = (const float*)d_in[1];
    const float* W10  = (const float*)d_in[2];
    const float* W11  = (const float*)d_in[3];
    const float* W12  = (const float*)d_in[4];
    const float* b1   = (const float*)d_in[5];
    const float* W20  = (const float*)d_in[6];
    const float* W21  = (const float*)d_in[7];
    const float* W22  = (const float*)d_in[8];
    const float* b2   = (const float*)d_in[9];
    float*  out = (float*)d_out;
    bf16_t* wf  = (bf16_t*)d_ws;

    int N = in_sizes[0] / 480;       // 100000

    prep_weights<<<dim3((W_TOTAL + 255) / 256), dim3(256), 0, stream>>>(
        W10, W11, W12, W20, W21, W22, wf);
    ffn_kernel<<<dim3(N / 16), dim3(256), 0, stream>>>(
        x, attr, b1, b2, wf, out);
}

// Round 5
// 462.996 us; speedup vs baseline: 1.0344x; 1.0344x over previous
//
#include <hip/hip_runtime.h>
#include <hip/hip_bf16.h>

typedef __bf16 bf16_t;
typedef __bf16 bf16x8 __attribute__((ext_vector_type(8)));
typedef float  f32x4  __attribute__((ext_vector_type(4)));

static __device__ __forceinline__ f32x4 mfma16(bf16x8 a, bf16x8 b, f32x4 c) {
    return __builtin_amdgcn_mfma_f32_16x16x32_bf16(a, b, c, 0, 0, 0);
}
static __device__ __forceinline__ float fast_rcp(float x) {
    return __builtin_amdgcn_rcpf(x);
}

// ws fragment-layout weight offsets (bf16 elements). Fragment block = 512
// elems = (64 lanes x 8 elems); block index = tile*frags + f.
#define OFF_W10 0
#define OFF_W11 86016
#define OFF_W12 98304
#define OFF_W20 101376
#define OFF_W21 150528
#define OFF_W22 162816
#define W_TOTAL 165888

// Coalesced-read weight prep: thread idx walks the SOURCE linearly,
// destination computed by inverting the fragment layout.
template<int K, int N, int OFF>
static __device__ __forceinline__ void scatter_seg(const float* __restrict__ src,
                                                   bf16_t* __restrict__ ws, int local) {
    int k  = local / N;            // constant N -> magic-mul
    int n  = local - k * N;
    int f  = k >> 5;
    int kr = k & 31;
    int lane = ((kr >> 3) << 4) | (n & 15);
    int dst  = OFF + ((((n >> 4) * (K >> 5)) + f) << 9) + (lane << 3) + (kr & 7);
    ws[dst] = (bf16_t)src[local];
}

__global__ void prep_weights(const float* __restrict__ W10, const float* __restrict__ W11,
                             const float* __restrict__ W12, const float* __restrict__ W20,
                             const float* __restrict__ W21, const float* __restrict__ W22,
                             bf16_t* __restrict__ ws) {
    int idx = blockIdx.x * 256 + threadIdx.x;
    if (idx >= W_TOTAL) return;
    if      (idx < OFF_W11) scatter_seg<128, 672, OFF_W10>(W10, ws, idx - OFF_W10);
    else if (idx < OFF_W12) scatter_seg< 64, 192, OFF_W11>(W11, ws, idx - OFF_W11);
    else if (idx < OFF_W20) scatter_seg< 32,  96, OFF_W12>(W12, ws, idx - OFF_W12);
    else if (idx < OFF_W21) scatter_seg<384, 128, OFF_W20>(W20, ws, idx - OFF_W20);
    else if (idx < OFF_W22) scatter_seg<192,  64, OFF_W21>(W21, ws, idx - OFF_W21);
    else                    scatter_seg< 96,  32, OFF_W22>(W22, ws, idx - OFF_W22);
}

// LDS plan (bf16 elems in smid, total 17920 = 35840 B):
//   [0,9600)     : xde (7808 used) during S0/S1, then mid1 (3 planes x 3200) in S2
//   [9600,17920) : mid0 (6272 used) in S1/S2, then mid2 (5 planes x 1664) in S3
// Gates in registers; biases in LDS. Total LDS 39104 B -> 4 blocks/CU.
// Latency plan: every phase's first weight tiles are prefetched into
// registers BEFORE the preceding barrier (loads stay in flight across
// s_barrier; only the consumer waits vmcnt), and S1 runs a depth-2
// register pipeline. This attacks the ~250-cycle L2 latency per weight
// tile that pinned MfmaUtil at 8%.
#define XDE_S   488
#define MID0_S  392
#define MID1_S  200
#define MID2_S  104
#define MID0_B  9600
#define MID2_B  9600

__global__ __launch_bounds__(256, 4)
void ffn_kernel(const float* __restrict__ x, const float* __restrict__ attr,
                const float* __restrict__ b1, const float* __restrict__ b2,
                const bf16_t* __restrict__ wf, float* __restrict__ out) {
    __shared__ bf16_t smid[17920];
    __shared__ float  sattr[16];
    __shared__ float  sb1[672];
    __shared__ float  sb2[128];

    const int tid   = threadIdx.x;
    const int lane  = tid & 63;
    const int w     = tid >> 6;
    const int rlane = lane & 15;
    const int q     = lane >> 4;
    const int rowbase = blockIdx.x * 16;

    // ---------------- S0: stage x (de-interleaved bf16), biases, attr ----
    for (int it = 0; it < 8; ++it) {
        int idx = tid + it * 256;
        if (idx < 1920) {
            int row = idx / 120;
            int c4  = idx - row * 120;
            const float4 v = ((const float4*)(x + (size_t)(rowbase + row) * 480))[c4];
            float vals[4] = {v.x, v.y, v.z, v.w};
            int base = c4 * 4;
#pragma unroll
            for (int e = 0; e < 4; ++e) {
                int col = base + e;
                int dc;
                if (col < 128) dc = col;
                else if (col < 320) { int r = col - 128; int m = r / 3; int i = r - m * 3; dc = 128 + i * 64 + m; }
                else                { int r = col - 320; int m = r / 5; int i = r - m * 5; dc = 320 + i * 32 + m; }
                smid[row * XDE_S + dc] = (bf16_t)vals[e];
            }
        }
    }
    for (int i = tid; i < 672; i += 256) sb1[i] = b1[i];
    if (tid < 128) sb2[tid] = b2[tid];
    if (tid < 16)  sattr[tid] = attr[rowbase + tid];
    __syncthreads();                                   // B1

    // Issue S1's first two weight tiles IMMEDIATELY (vmcnt work overlaps
    // the LDS fragment extraction below, which waits on lgkmcnt).
    const bf16_t* base10 = wf + OFF_W10 + (lane << 3);
    bf16x8 bc[4], bn[4];
    {
        const bf16_t* p0 = base10 + ((w * 4) << 9);
#pragma unroll
        for (int f = 0; f < 4; ++f) bc[f] = *(const bf16x8*)(p0 + (f << 9));
        const bf16_t* p1 = base10 + (((w + 4) * 4) << 9);
#pragma unroll
        for (int f = 0; f < 4; ++f) bn[f] = *(const bf16x8*)(p1 + (f << 9));
    }

    // per-wave attr registers (row = q*4 + r)
    float sat[4];
#pragma unroll
    for (int r = 0; r < 4; ++r) sat[r] = sattr[q * 4 + r];

    // ---------------- extract A fragments --------------------------------
    bf16x8 a0[4], a1[3][2], a2[5];
    {
        int rb = rlane * XDE_S + q * 8;
#pragma unroll
        for (int f = 0; f < 4; ++f) a0[f] = *(const bf16x8*)&smid[rb + f * 32];
#pragma unroll
        for (int i = 0; i < 3; ++i)
#pragma unroll
            for (int f = 0; f < 2; ++f) a1[i][f] = *(const bf16x8*)&smid[rb + 128 + i * 64 + f * 32];
#pragma unroll
        for (int i = 0; i < 5; ++i) a2[i] = *(const bf16x8*)&smid[rb + 320 + i * 32];
    }

    // sigmoid gates, register-resident, statically indexed. gv[k] <- P1l0
    // tile 24+w+4k; consumed by P1l1 (gv[0..2]) and P1l2 (gv[3..4]).
    float gv[5][4];

    // ---------------- S1: P1l0, depth-2 software pipeline -----------------
    {
        const float inv = 0.088388347648318447f;       // 1/sqrt(128)
#pragma unroll
        for (int ti = 0; ti < 11; ++ti) {
            int t = w + ti * 4;
            bf16x8 bf_[4] = {bn[0], bn[1], bn[2], bn[3]};
            if (ti < 9 && t + 8 < 42) {                // prefetch tile t+8
                const bf16_t* p = base10 + (((t + 8) * 4) << 9);
#pragma unroll
                for (int f = 0; f < 4; ++f) bf_[f] = *(const bf16x8*)(p + (f << 9));
            }
            if (t < 42) {                              // ti==10 only for w<2
                f32x4 acc = {0.f, 0.f, 0.f, 0.f};
#pragma unroll
                for (int f = 0; f < 4; ++f) acc = mfma16(a0[f], bc[f], acc);
                int c = t * 16 + rlane;
                float bias = sb1[c];
                if (ti < 6) {                          // t<24: scalars -> silu -> mid0
#pragma unroll
                    for (int r = 0; r < 4; ++r) {
                        float v = acc[r] * inv * sat[r] + bias;
                        float s = v * fast_rcp(1.f + __expf(-v));
                        smid[MID0_B + (q * 4 + r) * MID0_S + c] = (bf16_t)s;
                    }
                } else {                               // gates -> sigmoid -> regs
#pragma unroll
                    for (int r = 0; r < 4; ++r) {
                        float v = acc[r] * inv * sat[r] + bias;
                        gv[ti - 6][r] = fast_rcp(1.f + __expf(-v));
                    }
                }
            }
#pragma unroll
            for (int f = 0; f < 4; ++f) { bc[f] = bn[f]; bn[f] = bf_[f]; }
        }
    }

    // Cross-barrier prefetch for S2: first P2l0 tile (frags 0..3) and
    // first P1l1 tile. Loads issued here stay in flight across B2.
    bf16x8 pv20[4], pv11[2];
    {
        const bf16_t* p20 = wf + OFF_W20 + ((w * 12) << 9) + (lane << 3);
#pragma unroll
        for (int f = 0; f < 4; ++f) pv20[f] = *(const bf16x8*)(p20 + (f << 9));
        const bf16_t* p11 = wf + OFF_W11 + ((w * 2) << 9) + (lane << 3);
        pv11[0] = *(const bf16x8*)p11;
        pv11[1] = *(const bf16x8*)(p11 + 512);
    }
    __syncthreads();                                   // B2

    // ---------------- S2: P2l0 (out cols 0..127) + P1l1 (mid1) -----------
    {
        const float inv = 0.051031036307982884f;       // 1/sqrt(384)
        bf16x8 am[12];
        int rb = MID0_B + rlane * MID0_S + q * 8;
#pragma unroll
        for (int f = 0; f < 12; ++f) am[f] = *(const bf16x8*)&smid[rb + f * 32];
#pragma unroll
        for (int ti = 0; ti < 2; ++ti) {
            int t = w + ti * 4;
            const bf16_t* p = wf + OFF_W20 + ((t * 12) << 9) + (lane << 3);
            bf16x8 bfr[12];
            if (ti == 0) {
#pragma unroll
                for (int f = 0; f < 4; ++f) bfr[f] = pv20[f];
#pragma unroll
                for (int f = 4; f < 12; ++f) bfr[f] = *(const bf16x8*)(p + (f << 9));
            } else {
#pragma unroll
                for (int f = 0; f < 12; ++f) bfr[f] = *(const bf16x8*)(p + (f << 9));
            }
            float bias = sb2[t * 16 + rlane];
            f32x4 acc = {0.f, 0.f, 0.f, 0.f};
#pragma unroll
            for (int f = 0; f < 12; ++f) acc = mfma16(am[f], bfr[f], acc);
            int c = t * 16 + rlane;
#pragma unroll
            for (int r = 0; r < 4; ++r)
                out[(size_t)(rowbase + q * 4 + r) * 480 + c] = acc[r] * inv * sat[r] + bias;
        }
    }
    {
        const float inv = 0.125f;                      // 1/sqrt(64)
#pragma unroll
        for (int ti = 0; ti < 3; ++ti) {
            int t = w + ti * 4;
            const bf16_t* p = wf + OFF_W11 + ((t * 2) << 9) + (lane << 3);
            bf16x8 b0  = (ti == 0) ? pv11[0] : *(const bf16x8*)p;
            bf16x8 b1f = (ti == 0) ? pv11[1] : *(const bf16x8*)(p + 512);
            f32x4 acc[3];
#pragma unroll
            for (int i = 0; i < 3; ++i) {
                f32x4 a = {0.f, 0.f, 0.f, 0.f};
                a = mfma16(a1[i][0], b0, a);
                a = mfma16(a1[i][1], b1f, a);
                acc[i] = a;
            }
            int m = t * 16 + rlane;
#pragma unroll
            for (int r = 0; r < 4; ++r) {
                int row = q * 4 + r;
                float g = gv[ti][r] * inv * sat[r];
#pragma unroll
                for (int i = 0; i < 3; ++i)
                    smid[i * 3200 + row * MID1_S + m] = (bf16_t)(acc[i][r] * g);
            }
        }
    }

    // Cross-barrier prefetch for S3: W12 tile w and all of W21 tile w.
    bf16x8 pv12, pv21[6];
    {
        pv12 = *(const bf16x8*)(wf + OFF_W12 + (w << 9) + (lane << 3));
        const bf16_t* p21 = wf + OFF_W21 + ((w * 6) << 9) + (lane << 3);
#pragma unroll
        for (int f = 0; f < 6; ++f) pv21[f] = *(const bf16x8*)(p21 + (f << 9));
    }
    __syncthreads();                                   // B3

    // ---------------- S3: P1l2 (mid2) + P2l1 (out cols 128..319) ---------
    {
        const float inv = 0.17677669529663689f;        // 1/sqrt(32)
#pragma unroll
        for (int ti = 0; ti < 2; ++ti) {
            int t = w + ti * 4;
            if (ti == 1 && t >= 6) continue;           // waves 2,3: single tile
            bf16x8 b = (ti == 0) ? pv12
                                 : *(const bf16x8*)(wf + OFF_W12 + (t << 9) + (lane << 3));
            f32x4 acc[5];
#pragma unroll
            for (int i = 0; i < 5; ++i) {
                f32x4 a = {0.f, 0.f, 0.f, 0.f};
                acc[i] = mfma16(a2[i], b, a);
            }
            int m = t * 16 + rlane;
#pragma unroll
            for (int r = 0; r < 4; ++r) {
                int row = q * 4 + r;
                float g = gv[3 + ti][r] * inv * sat[r];
#pragma unroll
                for (int i = 0; i < 5; ++i)
                    smid[MID2_B + i * 1664 + row * MID2_S + m] = (bf16_t)(acc[i][r] * g);
            }
        }
    }
    {
        const float inv = 0.072168783648703220f;       // 1/sqrt(192)
        int t = w;                                     // 4 tiles exactly
        f32x4 acc[3];
#pragma unroll
        for (int i = 0; i < 3; ++i) {
            bf16x8 am[6];
            int rb = i * 3200 + rlane * MID1_S + q * 8;
#pragma unroll
            for (int f = 0; f < 6; ++f) am[f] = *(const bf16x8*)&smid[rb + f * 32];
            f32x4 a = {0.f, 0.f, 0.f, 0.f};
#pragma unroll
            for (int f = 0; f < 6; ++f) a = mfma16(am[f], pv21[f], a);
            acc[i] = a;
        }
        int o = t * 16 + rlane;
#pragma unroll
        for (int r = 0; r < 4; ++r) {
            float s = inv * sat[r];
            float* dst = out + (size_t)(rowbase + q * 4 + r) * 480 + 128 + o * 3;
            dst[0] = acc[0][r] * s;
            dst[1] = acc[1][r] * s;
            dst[2] = acc[2][r] * s;
        }
    }

    // Cross-barrier prefetch for S4 (only waves 0,1 participate).
    bf16x8 pv22[3];
    if (w < 2) {
        const bf16_t* p22 = wf + OFF_W22 + ((w * 3) << 9) + (lane << 3);
#pragma unroll
        for (int f = 0; f < 3; ++f) pv22[f] = *(const bf16x8*)(p22 + (f << 9));
    }
    __syncthreads();                                   // B4

    // ---------------- S4: P2l2 (out cols 320..479) -----------------------
    if (w < 2) {
        const float inv = 0.10206207261596575f;        // 1/sqrt(96)
        int t = w;                                     // 2 tiles
        f32x4 acc[5];
#pragma unroll
        for (int i = 0; i < 5; ++i) {
            bf16x8 am[3];
            int rb = MID2_B + i * 1664 + rlane * MID2_S + q * 8;
#pragma unroll
            for (int f = 0; f < 3; ++f) am[f] = *(const bf16x8*)&smid[rb + f * 32];
            f32x4 a = {0.f, 0.f, 0.f, 0.f};
#pragma unroll
            for (int f = 0; f < 3; ++f) a = mfma16(am[f], pv22[f], a);
            acc[i] = a;
        }
        int o = t * 16 + rlane;
#pragma unroll
        for (int r = 0; r < 4; ++r) {
            float s = inv * sat[r];
            float* dst = out + (size_t)(rowbase + q * 4 + r) * 480 + 320 + o * 5;
#pragma unroll
            for (int i = 0; i < 5; ++i) dst[i] = acc[i][r] * s;
        }
    }
}

extern "C" void kernel_launch(void* const* d_in, const int* in_sizes, int n_in,
                              void* d_out, int out_size, void* d_ws, size_t ws_size,
                              hipStream_t stream) {
    const float* x    = (const float*)d_in[0];
    const float* attr = (const float*)d_in[1];
    const float* W10  = (const float*)d_in[2];
    const float* W11  = (const float*)d_in[3];
    const float* W12  = (const float*)d_in[4];
    const float* b1   = (const float*)d_in[5];
    const float* W20  = (const float*)d_in[6];
    const float* W21  = (const float*)d_in[7];
    const float* W22  = (const float*)d_in[8];
    const float* b2   = (const float*)d_in[9];
    float*  out = (float*)d_out;
    bf16_t* wf  = (bf16_t*)d_ws;

    int N = in_sizes[0] / 480;       // 100000

    prep_weights<<<dim3((W_TOTAL + 255) / 256), dim3(256), 0, stream>>>(
        W10, W11, W12, W20, W21, W22, wf);
    ffn_kernel<<<dim3(N / 16), dim3(256), 0, stream>>>(
        x, attr, b1, b2, wf, out);
}

// Round 6
// 454.590 us; speedup vs baseline: 1.0535x; 1.0185x over previous
//
#include <hip/hip_runtime.h>
#include <hip/hip_bf16.h>

typedef __bf16 bf16_t;
typedef __bf16 bf16x8 __attribute__((ext_vector_type(8)));
typedef float  f32x4  __attribute__((ext_vector_type(4)));

static __device__ __forceinline__ f32x4 mfma16(bf16x8 a, bf16x8 b, f32x4 c) {
    return __builtin_amdgcn_mfma_f32_16x16x32_bf16(a, b, c, 0, 0, 0);
}
static __device__ __forceinline__ float fast_rcp(float x) {
    return __builtin_amdgcn_rcpf(x);
}

// ws fragment-layout weight offsets (bf16 elements). Fragment block = 512
// elems = (64 lanes x 8 elems); block index = tile*frags + f.
#define OFF_W10 0
#define OFF_W11 86016
#define OFF_W12 98304
#define OFF_W20 101376
#define OFF_W21 150528
#define OFF_W22 162816
#define W_TOTAL 165888

// Coalesced-read weight prep: thread idx walks the SOURCE linearly,
// destination computed by inverting the fragment layout.
template<int K, int N, int OFF>
static __device__ __forceinline__ void scatter_seg(const float* __restrict__ src,
                                                   bf16_t* __restrict__ ws, int local) {
    int k  = local / N;            // constant N -> magic-mul
    int n  = local - k * N;
    int f  = k >> 5;
    int kr = k & 31;
    int lane = ((kr >> 3) << 4) | (n & 15);
    int dst  = OFF + ((((n >> 4) * (K >> 5)) + f) << 9) + (lane << 3) + (kr & 7);
    ws[dst] = (bf16_t)src[local];
}

__global__ void prep_weights(const float* __restrict__ W10, const float* __restrict__ W11,
                             const float* __restrict__ W12, const float* __restrict__ W20,
                             const float* __restrict__ W21, const float* __restrict__ W22,
                             bf16_t* __restrict__ ws) {
    int idx = blockIdx.x * 256 + threadIdx.x;
    if (idx >= W_TOTAL) return;
    if      (idx < OFF_W11) scatter_seg<128, 672, OFF_W10>(W10, ws, idx - OFF_W10);
    else if (idx < OFF_W12) scatter_seg< 64, 192, OFF_W11>(W11, ws, idx - OFF_W11);
    else if (idx < OFF_W20) scatter_seg< 32,  96, OFF_W12>(W12, ws, idx - OFF_W12);
    else if (idx < OFF_W21) scatter_seg<384, 128, OFF_W20>(W20, ws, idx - OFF_W20);
    else if (idx < OFF_W22) scatter_seg<192,  64, OFF_W21>(W21, ws, idx - OFF_W21);
    else                    scatter_seg< 96,  32, OFF_W22>(W22, ws, idx - OFF_W22);
}

// LDS plan (bf16 elems in smid, total 17920 = 35840 B):
//   [0,9600)     : xde (7808 used) during S0/S1, then mid1 (3 planes x 3200) in S2
//   [9600,17920) : mid0 (6272 used) in S1/S2, then mid2 (5 planes x 1664) in S3
// Gates in registers; biases in LDS. Total LDS 39104 B.
// launch_bounds (256,3): the (256,4) variant capped VGPRs at 128 and the
// live pipeline state (A-frags for all 3 levels must outlive S1 because S2
// overwrites xde; + depth-2 prefetch + cross-barrier prefetch) spilled to
// scratch — visible as +100 MB WRITE / +50 MB FETCH vs round 0's clean
// 187.5 MB. At 170-VGPR cap the pipeline lives in registers.
#define XDE_S   488
#define MID0_S  392
#define MID1_S  200
#define MID2_S  104
#define MID0_B  9600
#define MID2_B  9600

__global__ __launch_bounds__(256, 3)
void ffn_kernel(const float* __restrict__ x, const float* __restrict__ attr,
                const float* __restrict__ b1, const float* __restrict__ b2,
                const bf16_t* __restrict__ wf, float* __restrict__ out) {
    __shared__ bf16_t smid[17920];
    __shared__ float  sattr[16];
    __shared__ float  sb1[672];
    __shared__ float  sb2[128];

    const int tid   = threadIdx.x;
    const int lane  = tid & 63;
    const int w     = tid >> 6;
    const int rlane = lane & 15;
    const int q     = lane >> 4;
    const int rowbase = blockIdx.x * 16;

    // ---------------- S0: stage x (de-interleaved bf16), biases, attr ----
    for (int it = 0; it < 8; ++it) {
        int idx = tid + it * 256;
        if (idx < 1920) {
            int row = idx / 120;
            int c4  = idx - row * 120;
            const float4 v = ((const float4*)(x + (size_t)(rowbase + row) * 480))[c4];
            float vals[4] = {v.x, v.y, v.z, v.w};
            int base = c4 * 4;
#pragma unroll
            for (int e = 0; e < 4; ++e) {
                int col = base + e;
                int dc;
                if (col < 128) dc = col;
                else if (col < 320) { int r = col - 128; int m = r / 3; int i = r - m * 3; dc = 128 + i * 64 + m; }
                else                { int r = col - 320; int m = r / 5; int i = r - m * 5; dc = 320 + i * 32 + m; }
                smid[row * XDE_S + dc] = (bf16_t)vals[e];
            }
        }
    }
    for (int i = tid; i < 672; i += 256) sb1[i] = b1[i];
    if (tid < 128) sb2[tid] = b2[tid];
    if (tid < 16)  sattr[tid] = attr[rowbase + tid];
    __syncthreads();                                   // B1

    // Issue S1's first two weight tiles IMMEDIATELY (vmcnt work overlaps
    // the LDS fragment extraction below, which waits on lgkmcnt).
    const bf16_t* base10 = wf + OFF_W10 + (lane << 3);
    bf16x8 bc[4], bn[4];
    {
        const bf16_t* p0 = base10 + ((w * 4) << 9);
#pragma unroll
        for (int f = 0; f < 4; ++f) bc[f] = *(const bf16x8*)(p0 + (f << 9));
        const bf16_t* p1 = base10 + (((w + 4) * 4) << 9);
#pragma unroll
        for (int f = 0; f < 4; ++f) bn[f] = *(const bf16x8*)(p1 + (f << 9));
    }

    // per-wave attr registers (row = q*4 + r)
    float sat[4];
#pragma unroll
    for (int r = 0; r < 4; ++r) sat[r] = sattr[q * 4 + r];

    // ---------------- extract A fragments --------------------------------
    bf16x8 a0[4], a1[3][2], a2[5];
    {
        int rb = rlane * XDE_S + q * 8;
#pragma unroll
        for (int f = 0; f < 4; ++f) a0[f] = *(const bf16x8*)&smid[rb + f * 32];
#pragma unroll
        for (int i = 0; i < 3; ++i)
#pragma unroll
            for (int f = 0; f < 2; ++f) a1[i][f] = *(const bf16x8*)&smid[rb + 128 + i * 64 + f * 32];
#pragma unroll
        for (int i = 0; i < 5; ++i) a2[i] = *(const bf16x8*)&smid[rb + 320 + i * 32];
    }

    // sigmoid gates, register-resident, statically indexed. gv[k] <- P1l0
    // tile 24+w+4k; consumed by P1l1 (gv[0..2]) and P1l2 (gv[3..4]).
    float gv[5][4];

    // ---------------- S1: P1l0, depth-2 software pipeline -----------------
    {
        const float inv = 0.088388347648318447f;       // 1/sqrt(128)
#pragma unroll
        for (int ti = 0; ti < 11; ++ti) {
            int t = w + ti * 4;
            bf16x8 bf_[4] = {bn[0], bn[1], bn[2], bn[3]};
            if (ti < 9 && t + 8 < 42) {                // prefetch tile t+8
                const bf16_t* p = base10 + (((t + 8) * 4) << 9);
#pragma unroll
                for (int f = 0; f < 4; ++f) bf_[f] = *(const bf16x8*)(p + (f << 9));
            }
            if (t < 42) {                              // ti==10 only for w<2
                f32x4 acc = {0.f, 0.f, 0.f, 0.f};
#pragma unroll
                for (int f = 0; f < 4; ++f) acc = mfma16(a0[f], bc[f], acc);
                int c = t * 16 + rlane;
                float bias = sb1[c];
                if (ti < 6) {                          // t<24: scalars -> silu -> mid0
#pragma unroll
                    for (int r = 0; r < 4; ++r) {
                        float v = acc[r] * inv * sat[r] + bias;
                        float s = v * fast_rcp(1.f + __expf(-v));
                        smid[MID0_B + (q * 4 + r) * MID0_S + c] = (bf16_t)s;
                    }
                } else {                               // gates -> sigmoid -> regs
#pragma unroll
                    for (int r = 0; r < 4; ++r) {
                        float v = acc[r] * inv * sat[r] + bias;
                        gv[ti - 6][r] = fast_rcp(1.f + __expf(-v));
                    }
                }
            }
#pragma unroll
            for (int f = 0; f < 4; ++f) { bc[f] = bn[f]; bn[f] = bf_[f]; }
        }
    }

    // Cross-barrier prefetch for S2: first P2l0 tile (frags 0..3) and
    // first P1l1 tile. Loads issued here stay in flight across B2.
    bf16x8 pv20[4], pv11[2];
    {
        const bf16_t* p20 = wf + OFF_W20 + ((w * 12) << 9) + (lane << 3);
#pragma unroll
        for (int f = 0; f < 4; ++f) pv20[f] = *(const bf16x8*)(p20 + (f << 9));
        const bf16_t* p11 = wf + OFF_W11 + ((w * 2) << 9) + (lane << 3);
        pv11[0] = *(const bf16x8*)p11;
        pv11[1] = *(const bf16x8*)(p11 + 512);
    }
    __syncthreads();                                   // B2

    // ---------------- S2: P2l0 (out cols 0..127) + P1l1 (mid1) -----------
    {
        const float inv = 0.051031036307982884f;       // 1/sqrt(384)
        bf16x8 am[12];
        int rb = MID0_B + rlane * MID0_S + q * 8;
#pragma unroll
        for (int f = 0; f < 12; ++f) am[f] = *(const bf16x8*)&smid[rb + f * 32];
#pragma unroll
        for (int ti = 0; ti < 2; ++ti) {
            int t = w + ti * 4;
            const bf16_t* p = wf + OFF_W20 + ((t * 12) << 9) + (lane << 3);
            bf16x8 bfr[12];
            if (ti == 0) {
#pragma unroll
                for (int f = 0; f < 4; ++f) bfr[f] = pv20[f];
#pragma unroll
                for (int f = 4; f < 12; ++f) bfr[f] = *(const bf16x8*)(p + (f << 9));
            } else {
#pragma unroll
                for (int f = 0; f < 12; ++f) bfr[f] = *(const bf16x8*)(p + (f << 9));
            }
            float bias = sb2[t * 16 + rlane];
            f32x4 acc = {0.f, 0.f, 0.f, 0.f};
#pragma unroll
            for (int f = 0; f < 12; ++f) acc = mfma16(am[f], bfr[f], acc);
            int c = t * 16 + rlane;
#pragma unroll
            for (int r = 0; r < 4; ++r)
                out[(size_t)(rowbase + q * 4 + r) * 480 + c] = acc[r] * inv * sat[r] + bias;
        }
    }
    {
        const float inv = 0.125f;                      // 1/sqrt(64)
#pragma unroll
        for (int ti = 0; ti < 3; ++ti) {
            int t = w + ti * 4;
            const bf16_t* p = wf + OFF_W11 + ((t * 2) << 9) + (lane << 3);
            bf16x8 b0  = (ti == 0) ? pv11[0] : *(const bf16x8*)p;
            bf16x8 b1f = (ti == 0) ? pv11[1] : *(const bf16x8*)(p + 512);
            f32x4 acc[3];
#pragma unroll
            for (int i = 0; i < 3; ++i) {
                f32x4 a = {0.f, 0.f, 0.f, 0.f};
                a = mfma16(a1[i][0], b0, a);
                a = mfma16(a1[i][1], b1f, a);
                acc[i] = a;
            }
            int m = t * 16 + rlane;
#pragma unroll
            for (int r = 0; r < 4; ++r) {
                int row = q * 4 + r;
                float g = gv[ti][r] * inv * sat[r];
#pragma unroll
                for (int i = 0; i < 3; ++i)
                    smid[i * 3200 + row * MID1_S + m] = (bf16_t)(acc[i][r] * g);
            }
        }
    }

    // Cross-barrier prefetch for S3: W12 tile w and all of W21 tile w.
    bf16x8 pv12, pv21[6];
    {
        pv12 = *(const bf16x8*)(wf + OFF_W12 + (w << 9) + (lane << 3));
        const bf16_t* p21 = wf + OFF_W21 + ((w * 6) << 9) + (lane << 3);
#pragma unroll
        for (int f = 0; f < 6; ++f) pv21[f] = *(const bf16x8*)(p21 + (f << 9));
    }
    __syncthreads();                                   // B3

    // ---------------- S3: P1l2 (mid2) + P2l1 (out cols 128..319) ---------
    {
        const float inv = 0.17677669529663689f;        // 1/sqrt(32)
#pragma unroll
        for (int ti = 0; ti < 2; ++ti) {
            int t = w + ti * 4;
            if (ti == 1 && t >= 6) continue;           // waves 2,3: single tile
            bf16x8 b = (ti == 0) ? pv12
                                 : *(const bf16x8*)(wf + OFF_W12 + (t << 9) + (lane << 3));
            f32x4 acc[5];
#pragma unroll
            for (int i = 0; i < 5; ++i) {
                f32x4 a = {0.f, 0.f, 0.f, 0.f};
                acc[i] = mfma16(a2[i], b, a);
            }
            int m = t * 16 + rlane;
#pragma unroll
            for (int r = 0; r < 4; ++r) {
                int row = q * 4 + r;
                float g = gv[3 + ti][r] * inv * sat[r];
#pragma unroll
                for (int i = 0; i < 5; ++i)
                    smid[MID2_B + i * 1664 + row * MID2_S + m] = (bf16_t)(acc[i][r] * g);
            }
        }
    }
    {
        const float inv = 0.072168783648703220f;       // 1/sqrt(192)
        int t = w;                                     // 4 tiles exactly
        f32x4 acc[3];
#pragma unroll
        for (int i = 0; i < 3; ++i) {
            bf16x8 am[6];
            int rb = i * 3200 + rlane * MID1_S + q * 8;
#pragma unroll
            for (int f = 0; f < 6; ++f) am[f] = *(const bf16x8*)&smid[rb + f * 32];
            f32x4 a = {0.f, 0.f, 0.f, 0.f};
#pragma unroll
            for (int f = 0; f < 6; ++f) a = mfma16(am[f], pv21[f], a);
            acc[i] = a;
        }
        int o = t * 16 + rlane;
#pragma unroll
        for (int r = 0; r < 4; ++r) {
            float s = inv * sat[r];
            float* dst = out + (size_t)(rowbase + q * 4 + r) * 480 + 128 + o * 3;
            dst[0] = acc[0][r] * s;
            dst[1] = acc[1][r] * s;
            dst[2] = acc[2][r] * s;
        }
    }

    // Cross-barrier prefetch for S4 (only waves 0,1 participate).
    bf16x8 pv22[3];
    if (w < 2) {
        const bf16_t* p22 = wf + OFF_W22 + ((w * 3) << 9) + (lane << 3);
#pragma unroll
        for (int f = 0; f < 3; ++f) pv22[f] = *(const bf16x8*)(p22 + (f << 9));
    }
    __syncthreads();                                   // B4

    // ---------------- S4: P2l2 (out cols 320..479) -----------------------
    if (w < 2) {
        const float inv = 0.10206207261596575f;        // 1/sqrt(96)
        int t = w;                                     // 2 tiles
        f32x4 acc[5];
#pragma unroll
        for (int i = 0; i < 5; ++i) {
            bf16x8 am[3];
            int rb = MID2_B + i * 1664 + rlane * MID2_S + q * 8;
#pragma unroll
            for (int f = 0; f < 3; ++f) am[f] = *(const bf16x8*)&smid[rb + f * 32];
            f32x4 a = {0.f, 0.f, 0.f, 0.f};
#pragma unroll
            for (int f = 0; f < 3; ++f) a = mfma16(am[f], pv22[f], a);
            acc[i] = a;
        }
        int o = t * 16 + rlane;
#pragma unroll
        for (int r = 0; r < 4; ++r) {
            float s = inv * sat[r];
            float* dst = out + (size_t)(rowbase + q * 4 + r) * 480 + 320 + o * 5;
#pragma unroll
            for (int i = 0; i < 5; ++i) dst[i] = acc[i][r] * s;
        }
    }
}

extern "C" void kernel_launch(void* const* d_in, const int* in_sizes, int n_in,
                              void* d_out, int out_size, void* d_ws, size_t ws_size,
                              hipStream_t stream) {
    const float* x    = (const float*)d_in[0];
    const float* attr = (const float*)d_in[1];
    const float* W10  = (const float*)d_in[2];
    const float* W11  = (const float*)d_in[3];
    const float* W12  = (const float*)d_in[4];
    const float* b1   = (const float*)d_in[5];
    const float* W20  = (const float*)d_in[6];
    const float* W21  = (const float*)d_in[7];
    const float* W22  = (const float*)d_in[8];
    const float* b2   = (const float*)d_in[9];
    float*  out = (float*)d_out;
    bf16_t* wf  = (bf16_t*)d_ws;

    int N = in_sizes[0] / 480;       // 100000

    prep_weights<<<dim3((W_TOTAL + 255) / 256), dim3(256), 0, stream>>>(
        W10, W11, W12, W20, W21, W22, wf);
    ffn_kernel<<<dim3(N / 16), dim3(256), 0, stream>>>(
        x, attr, b1, b2, wf, out);
}

// Round 7
// 449.237 us; speedup vs baseline: 1.0660x; 1.0119x over previous
//
#include <hip/hip_runtime.h>
#include <hip/hip_bf16.h>

typedef __bf16 bf16_t;
typedef __bf16 bf16x8 __attribute__((ext_vector_type(8)));
typedef float  f32x4  __attribute__((ext_vector_type(4)));

static __device__ __forceinline__ f32x4 mfma16(bf16x8 a, bf16x8 b, f32x4 c) {
    return __builtin_amdgcn_mfma_f32_16x16x32_bf16(a, b, c, 0, 0, 0);
}
static __device__ __forceinline__ float fast_rcp(float x) {
    return __builtin_amdgcn_rcpf(x);
}

// ws fragment-layout weight offsets (bf16 elements). Fragment block = 512
// elems = (64 lanes x 8 elems); block index = tile*frags + f.
#define OFF_W10 0
#define OFF_W11 86016
#define OFF_W12 98304
#define OFF_W20 101376
#define OFF_W21 150528
#define OFF_W22 162816
#define W_TOTAL 165888

// Coalesced-read weight prep: thread idx walks the SOURCE linearly,
// destination computed by inverting the fragment layout.
template<int K, int N, int OFF>
static __device__ __forceinline__ void scatter_seg(const float* __restrict__ src,
                                                   bf16_t* __restrict__ ws, int local) {
    int k  = local / N;            // constant N -> magic-mul
    int n  = local - k * N;
    int f  = k >> 5;
    int kr = k & 31;
    int lane = ((kr >> 3) << 4) | (n & 15);
    int dst  = OFF + ((((n >> 4) * (K >> 5)) + f) << 9) + (lane << 3) + (kr & 7);
    ws[dst] = (bf16_t)src[local];
}

__global__ void prep_weights(const float* __restrict__ W10, const float* __restrict__ W11,
                             const float* __restrict__ W12, const float* __restrict__ W20,
                             const float* __restrict__ W21, const float* __restrict__ W22,
                             bf16_t* __restrict__ ws) {
    int idx = blockIdx.x * 256 + threadIdx.x;
    if (idx >= W_TOTAL) return;
    if      (idx < OFF_W11) scatter_seg<128, 672, OFF_W10>(W10, ws, idx - OFF_W10);
    else if (idx < OFF_W12) scatter_seg< 64, 192, OFF_W11>(W11, ws, idx - OFF_W11);
    else if (idx < OFF_W20) scatter_seg< 32,  96, OFF_W12>(W12, ws, idx - OFF_W12);
    else if (idx < OFF_W21) scatter_seg<384, 128, OFF_W20>(W20, ws, idx - OFF_W20);
    else if (idx < OFF_W22) scatter_seg<192,  64, OFF_W21>(W21, ws, idx - OFF_W21);
    else                    scatter_seg< 96,  32, OFF_W22>(W22, ws, idx - OFF_W22);
}

// 32-row block, 4 waves: waves 0-1 -> rows 0-15 (half 0), waves 2-3 ->
// rows 16-31 (half 1). Each half owns a 17920-elem smid arena with the
// proven overlay plan (xde -> mid1 in S2, mid0 -> mid2 in S3; all A-frags
// extracted up-front so overlays are race-free). Per wave, tile counts
// double vs the 16-row kernel: S1=21 iters (depth-3 pipeline), S2=4+6,
// S3=3+2, S4=1 — perfect 2-way balance in every phase, and each weight
// fetch now serves 32 rows (halved L2 weight stream).
// launch_bounds(256,2): VGPR cap 256 — pipeline state fully resident.
#define HALF_E  17920
#define XDE_S   488
#define MID0_S  392
#define MID1_S  200
#define MID2_S  104
#define MID0_B  9600
#define MID2_B  9600

__global__ __launch_bounds__(256, 2)
void ffn_kernel(const float* __restrict__ x, const float* __restrict__ attr,
                const float* __restrict__ b1, const float* __restrict__ b2,
                const bf16_t* __restrict__ wf, float* __restrict__ out) {
    __shared__ bf16_t smid[2 * HALF_E];
    __shared__ float  sattr[32];
    __shared__ float  sb1[672];
    __shared__ float  sb2[128];

    const int tid   = threadIdx.x;
    const int lane  = tid & 63;
    const int w     = tid >> 6;
    const int wl    = w & 1;       // wave-in-half: 0/1
    const int half  = w >> 1;      // row half: 0/1
    const int rlane = lane & 15;
    const int q     = lane >> 4;
    const int rowbase = blockIdx.x * 32;
    const int rowh    = rowbase + half * 16;

    // ---------------- S0: stage 32 rows (de-interleaved bf16) -------------
#pragma unroll
    for (int it = 0; it < 15; ++it) {                  // 15*256 = 3840 exact
        int idx = tid + it * 256;
        int row = idx / 120;
        int c4  = idx - row * 120;
        const float4 v = ((const float4*)(x + (size_t)(rowbase + row) * 480))[c4];
        float vals[4] = {v.x, v.y, v.z, v.w};
        int sbase = (row >> 4) * HALF_E + (row & 15) * XDE_S;
        int base = c4 * 4;
#pragma unroll
        for (int e = 0; e < 4; ++e) {
            int col = base + e;
            int dc;
            if (col < 128) dc = col;
            else if (col < 320) { int r = col - 128; int m = r / 3; int i = r - m * 3; dc = 128 + i * 64 + m; }
            else                { int r = col - 320; int m = r / 5; int i = r - m * 5; dc = 320 + i * 32 + m; }
            smid[sbase + dc] = (bf16_t)vals[e];
        }
    }
    for (int i = tid; i < 672; i += 256) sb1[i] = b1[i];
    if (tid < 128) sb2[tid] = b2[tid];
    if (tid < 32)  sattr[tid] = attr[rowbase + tid];
    __syncthreads();                                   // B1

    bf16_t* sm = smid + half * HALF_E;

    // Issue S1's first three weight tiles immediately (depth-3 pipeline;
    // vmcnt work overlaps the LDS fragment extraction below).
    const bf16_t* base10 = wf + OFF_W10 + (lane << 3);
    bf16x8 bc[4], bn[4], b2f[4];
    {
        const bf16_t* p0 = base10 + ((wl * 4) << 9);
        const bf16_t* p1 = base10 + (((wl + 2) * 4) << 9);
        const bf16_t* p2 = base10 + (((wl + 4) * 4) << 9);
#pragma unroll
        for (int f = 0; f < 4; ++f) bc[f]  = *(const bf16x8*)(p0 + (f << 9));
#pragma unroll
        for (int f = 0; f < 4; ++f) bn[f]  = *(const bf16x8*)(p1 + (f << 9));
#pragma unroll
        for (int f = 0; f < 4; ++f) b2f[f] = *(const bf16x8*)(p2 + (f << 9));
    }

    // per-wave attr registers (row = rowh + q*4 + r)
    float sat[4];
#pragma unroll
    for (int r = 0; r < 4; ++r) sat[r] = sattr[half * 16 + q * 4 + r];

    // ---------------- extract A fragments (all up-front) ------------------
    bf16x8 a0[4], a1[3][2], a2[5];
    {
        int rb = rlane * XDE_S + q * 8;
#pragma unroll
        for (int f = 0; f < 4; ++f) a0[f] = *(const bf16x8*)&sm[rb + f * 32];
#pragma unroll
        for (int i = 0; i < 3; ++i)
#pragma unroll
            for (int f = 0; f < 2; ++f) a1[i][f] = *(const bf16x8*)&sm[rb + 128 + i * 64 + f * 32];
#pragma unroll
        for (int i = 0; i < 5; ++i) a2[i] = *(const bf16x8*)&sm[rb + 320 + i * 32];
    }

    // sigmoid gates in registers. gv[k] <- S1 iter 12+k (gate tile 24+wl+2k);
    // consumed by P1l1 (gv[0..5]) and P1l2 (gv[6..8]). Same wave, same lane.
    float gv[9][4];

    // ---------------- S1: P1l0, 21 iters, depth-3 pipeline ----------------
    {
        const float inv = 0.088388347648318447f;       // 1/sqrt(128)
#pragma unroll
        for (int ti = 0; ti < 21; ++ti) {
            int t = wl + ti * 2;
            bf16x8 bf_[4] = {b2f[0], b2f[1], b2f[2], b2f[3]};
            if (ti < 18) {                             // prefetch tile t+6
                const bf16_t* p = base10 + (((t + 6) * 4) << 9);
#pragma unroll
                for (int f = 0; f < 4; ++f) bf_[f] = *(const bf16x8*)(p + (f << 9));
            }
            f32x4 acc = {0.f, 0.f, 0.f, 0.f};
#pragma unroll
            for (int f = 0; f < 4; ++f) acc = mfma16(a0[f], bc[f], acc);
            int c = t * 16 + rlane;
            float bias = sb1[c];
            if (ti < 12) {                             // t<24: scalars -> silu -> mid0
#pragma unroll
                for (int r = 0; r < 4; ++r) {
                    float v = acc[r] * inv * sat[r] + bias;
                    float s = v * fast_rcp(1.f + __expf(-v));
                    sm[MID0_B + (q * 4 + r) * MID0_S + c] = (bf16_t)s;
                }
            } else {                                   // gates -> sigmoid -> regs
#pragma unroll
                for (int r = 0; r < 4; ++r) {
                    float v = acc[r] * inv * sat[r] + bias;
                    gv[ti - 12][r] = fast_rcp(1.f + __expf(-v));
                }
            }
#pragma unroll
            for (int f = 0; f < 4; ++f) { bc[f] = bn[f]; bn[f] = b2f[f]; b2f[f] = bf_[f]; }
        }
    }

    // Cross-barrier prefetch for S2: first P2l0 tile (frags 0..3) and
    // first P1l1 tile. Loads stay in flight across B2.
    bf16x8 pv20[4], pv11[2];
    {
        const bf16_t* p20 = wf + OFF_W20 + ((wl * 12) << 9) + (lane << 3);
#pragma unroll
        for (int f = 0; f < 4; ++f) pv20[f] = *(const bf16x8*)(p20 + (f << 9));
        const bf16_t* p11 = wf + OFF_W11 + ((wl * 2) << 9) + (lane << 3);
        pv11[0] = *(const bf16x8*)p11;
        pv11[1] = *(const bf16x8*)(p11 + 512);
    }
    __syncthreads();                                   // B2

    // ---------------- S2: P2l0 (out cols 0..127, 4 tiles) + P1l1 (6 tiles)
    {
        const float inv = 0.051031036307982884f;       // 1/sqrt(384)
        bf16x8 am[12];
        int rb = MID0_B + rlane * MID0_S + q * 8;
#pragma unroll
        for (int f = 0; f < 12; ++f) am[f] = *(const bf16x8*)&sm[rb + f * 32];
#pragma unroll
        for (int ti = 0; ti < 4; ++ti) {
            int t = wl + ti * 2;
            const bf16_t* p = wf + OFF_W20 + ((t * 12) << 9) + (lane << 3);
            bf16x8 bfr[12];
            if (ti == 0) {
#pragma unroll
                for (int f = 0; f < 4; ++f) bfr[f] = pv20[f];
#pragma unroll
                for (int f = 4; f < 12; ++f) bfr[f] = *(const bf16x8*)(p + (f << 9));
            } else {
#pragma unroll
                for (int f = 0; f < 12; ++f) bfr[f] = *(const bf16x8*)(p + (f << 9));
            }
            float bias = sb2[t * 16 + rlane];
            f32x4 acc = {0.f, 0.f, 0.f, 0.f};
#pragma unroll
            for (int f = 0; f < 12; ++f) acc = mfma16(am[f], bfr[f], acc);
            int c = t * 16 + rlane;
#pragma unroll
            for (int r = 0; r < 4; ++r)
                out[(size_t)(rowh + q * 4 + r) * 480 + c] = acc[r] * inv * sat[r] + bias;
        }
    }
    {
        const float inv = 0.125f;                      // 1/sqrt(64)
#pragma unroll
        for (int ti = 0; ti < 6; ++ti) {
            int t = wl + ti * 2;
            const bf16_t* p = wf + OFF_W11 + ((t * 2) << 9) + (lane << 3);
            bf16x8 b0  = (ti == 0) ? pv11[0] : *(const bf16x8*)p;
            bf16x8 b1f = (ti == 0) ? pv11[1] : *(const bf16x8*)(p + 512);
            f32x4 acc[3];
#pragma unroll
            for (int i = 0; i < 3; ++i) {
                f32x4 a = {0.f, 0.f, 0.f, 0.f};
                a = mfma16(a1[i][0], b0, a);
                a = mfma16(a1[i][1], b1f, a);
                acc[i] = a;
            }
            int m = t * 16 + rlane;
#pragma unroll
            for (int r = 0; r < 4; ++r) {
                int row = q * 4 + r;
                float g = gv[ti][r] * inv * sat[r];
#pragma unroll
                for (int i = 0; i < 3; ++i)
                    sm[i * 3200 + row * MID1_S + m] = (bf16_t)(acc[i][r] * g);
            }
        }
    }

    // Cross-barrier prefetch for S3: W12 tile wl and full W21 tile wl.
    bf16x8 pv12, pv21[6];
    {
        pv12 = *(const bf16x8*)(wf + OFF_W12 + (wl << 9) + (lane << 3));
        const bf16_t* p21 = wf + OFF_W21 + ((wl * 6) << 9) + (lane << 3);
#pragma unroll
        for (int f = 0; f < 6; ++f) pv21[f] = *(const bf16x8*)(p21 + (f << 9));
    }
    __syncthreads();                                   // B3

    // ---------------- S3: P1l2 (mid2, 3 tiles) + P2l1 (2 tiles) ----------
    {
        const float inv = 0.17677669529663689f;        // 1/sqrt(32)
#pragma unroll
        for (int tj = 0; tj < 3; ++tj) {
            int t = wl + tj * 2;
            bf16x8 b = (tj == 0) ? pv12
                                 : *(const bf16x8*)(wf + OFF_W12 + (t << 9) + (lane << 3));
            f32x4 acc[5];
#pragma unroll
            for (int i = 0; i < 5; ++i) {
                f32x4 a = {0.f, 0.f, 0.f, 0.f};
                acc[i] = mfma16(a2[i], b, a);
            }
            int m = t * 16 + rlane;
#pragma unroll
            for (int r = 0; r < 4; ++r) {
                int row = q * 4 + r;
                float g = gv[6 + tj][r] * inv * sat[r];
#pragma unroll
                for (int i = 0; i < 5; ++i)
                    sm[MID2_B + i * 1664 + row * MID2_S + m] = (bf16_t)(acc[i][r] * g);
            }
        }
    }
    {
        const float inv = 0.072168783648703220f;       // 1/sqrt(192)
        bf16x8 am21[3][6];
#pragma unroll
        for (int i = 0; i < 3; ++i) {
            int rb = i * 3200 + rlane * MID1_S + q * 8;
#pragma unroll
            for (int f = 0; f < 6; ++f) am21[i][f] = *(const bf16x8*)&sm[rb + f * 32];
        }
#pragma unroll
        for (int ti = 0; ti < 2; ++ti) {
            int t = wl + ti * 2;
            bf16x8 b[6];
            if (ti == 0) {
#pragma unroll
                for (int f = 0; f < 6; ++f) b[f] = pv21[f];
            } else {
                const bf16_t* p = wf + OFF_W21 + ((t * 6) << 9) + (lane << 3);
#pragma unroll
                for (int f = 0; f < 6; ++f) b[f] = *(const bf16x8*)(p + (f << 9));
            }
            f32x4 acc[3];
#pragma unroll
            for (int i = 0; i < 3; ++i) {
                f32x4 a = {0.f, 0.f, 0.f, 0.f};
#pragma unroll
                for (int f = 0; f < 6; ++f) a = mfma16(am21[i][f], b[f], a);
                acc[i] = a;
            }
            int o = t * 16 + rlane;
#pragma unroll
            for (int r = 0; r < 4; ++r) {
                float s = inv * sat[r];
                float* dst = out + (size_t)(rowh + q * 4 + r) * 480 + 128 + o * 3;
                dst[0] = acc[0][r] * s;
                dst[1] = acc[1][r] * s;
                dst[2] = acc[2][r] * s;
            }
        }
    }

    // Cross-barrier prefetch for S4 (both waves of each half: tile wl).
    bf16x8 pv22[3];
    {
        const bf16_t* p22 = wf + OFF_W22 + ((wl * 3) << 9) + (lane << 3);
#pragma unroll
        for (int f = 0; f < 3; ++f) pv22[f] = *(const bf16x8*)(p22 + (f << 9));
    }
    __syncthreads();                                   // B4

    // ---------------- S4: P2l2 (out cols 320..479, 1 tile/wave) ----------
    {
        const float inv = 0.10206207261596575f;        // 1/sqrt(96)
        int t = wl;
        f32x4 acc[5];
#pragma unroll
        for (int i = 0; i < 5; ++i) {
            bf16x8 am[3];
            int rb = MID2_B + i * 1664 + rlane * MID2_S + q * 8;
#pragma unroll
            for (int f = 0; f < 3; ++f) am[f] = *(const bf16x8*)&sm[rb + f * 32];
            f32x4 a = {0.f, 0.f, 0.f, 0.f};
#pragma unroll
            for (int f = 0; f < 3; ++f) a = mfma16(am[f], pv22[f], a);
            acc[i] = a;
        }
        int o = t * 16 + rlane;
#pragma unroll
        for (int r = 0; r < 4; ++r) {
            float s = inv * sat[r];
            float* dst = out + (size_t)(rowh + q * 4 + r) * 480 + 320 + o * 5;
#pragma unroll
            for (int i = 0; i < 5; ++i) dst[i] = acc[i][r] * s;
        }
    }
}

extern "C" void kernel_launch(void* const* d_in, const int* in_sizes, int n_in,
                              void* d_out, int out_size, void* d_ws, size_t ws_size,
                              hipStream_t stream) {
    const float* x    = (const float*)d_in[0];
    const float* attr = (const float*)d_in[1];
    const float* W10  = (const float*)d_in[2];
    const float* W11  = (const float*)d_in[3];
    const float* W12  = (const float*)d_in[4];
    const float* b1   = (const float*)d_in[5];
    const float* W20  = (const float*)d_in[6];
    const float* W21  = (const float*)d_in[7];
    const float* W22  = (const float*)d_in[8];
    const float* b2   = (const float*)d_in[9];
    float*  out = (float*)d_out;
    bf16_t* wf  = (bf16_t*)d_ws;

    int N = in_sizes[0] / 480;       // 100000

    prep_weights<<<dim3((W_TOTAL + 255) / 256), dim3(256), 0, stream>>>(
        W10, W11, W12, W20, W21, W22, wf);
    ffn_kernel<<<dim3(N / 32), dim3(256), 0, stream>>>(
        x, attr, b1, b2, wf, out);
}

// Round 8
// 448.739 us; speedup vs baseline: 1.0672x; 1.0011x over previous
//
#include <hip/hip_runtime.h>
#include <hip/hip_bf16.h>

typedef __bf16 bf16_t;
typedef __bf16 bf16x8 __attribute__((ext_vector_type(8)));
typedef float  f32x4  __attribute__((ext_vector_type(4)));

static __device__ __forceinline__ f32x4 mfma16(bf16x8 a, bf16x8 b, f32x4 c) {
    return __builtin_amdgcn_mfma_f32_16x16x32_bf16(a, b, c, 0, 0, 0);
}
static __device__ __forceinline__ float fast_rcp(float x) {
    return __builtin_amdgcn_rcpf(x);
}

// ws fragment-layout weight offsets (bf16 elements). Fragment block = 512
// elems = (64 lanes x 8 elems); block index = tile*frags + f.
#define OFF_W10 0
#define OFF_W11 86016
#define OFF_W12 98304
#define OFF_W20 101376
#define OFF_W21 150528
#define OFF_W22 162816
#define W_TOTAL 165888

// Coalesced-read weight prep: thread idx walks the SOURCE linearly,
// destination computed by inverting the fragment layout.
template<int K, int N, int OFF>
static __device__ __forceinline__ void scatter_seg(const float* __restrict__ src,
                                                   bf16_t* __restrict__ ws, int local) {
    int k  = local / N;            // constant N -> magic-mul
    int n  = local - k * N;
    int f  = k >> 5;
    int kr = k & 31;
    int lane = ((kr >> 3) << 4) | (n & 15);
    int dst  = OFF + ((((n >> 4) * (K >> 5)) + f) << 9) + (lane << 3) + (kr & 7);
    ws[dst] = (bf16_t)src[local];
}

__global__ void prep_weights(const float* __restrict__ W10, const float* __restrict__ W11,
                             const float* __restrict__ W12, const float* __restrict__ W20,
                             const float* __restrict__ W21, const float* __restrict__ W22,
                             bf16_t* __restrict__ ws) {
    int idx = blockIdx.x * 256 + threadIdx.x;
    if (idx >= W_TOTAL) return;
    if      (idx < OFF_W11) scatter_seg<128, 672, OFF_W10>(W10, ws, idx - OFF_W10);
    else if (idx < OFF_W12) scatter_seg< 64, 192, OFF_W11>(W11, ws, idx - OFF_W11);
    else if (idx < OFF_W20) scatter_seg< 32,  96, OFF_W12>(W12, ws, idx - OFF_W12);
    else if (idx < OFF_W21) scatter_seg<384, 128, OFF_W20>(W20, ws, idx - OFF_W20);
    else if (idx < OFF_W22) scatter_seg<192,  64, OFF_W21>(W21, ws, idx - OFF_W21);
    else                    scatter_seg< 96,  32, OFF_W22>(W22, ws, idx - OFF_W22);
}

// 32-row block, 4 waves: waves 0-1 -> rows 0-15 (half 0), waves 2-3 ->
// rows 16-31 (half 1). Each half owns a 17920-elem smid arena (overlay:
// xde -> mid1 in S2, mid0 -> mid2 in S3; A-frags extracted up-front).
// Round 8: every phase's weight stream is register-pipelined — S1 depth-3
// (as before); S2 pre-B2 prefetch of P1l1 tiles 0-1 + P2l0 tile 0, tile 1
// issued right after B2 (flies over P1l1), rolling depth-2 in both loops;
// S3 all P1l2 weights + P2l1 tile 0 pre-B3, tile 1 post-B3 (hidden under
// P1l2); S4 prefetched pre-B4. Targets the 62% SIMD-idle (29 VALU + 9
// MFMA busy) measured in r7 — exposed L2 latency + barrier convoy.
#define HALF_E  17920
#define XDE_S   488
#define MID0_S  392
#define MID1_S  200
#define MID2_S  104
#define MID0_B  9600
#define MID2_B  9600

__global__ __launch_bounds__(256, 2)
void ffn_kernel(const float* __restrict__ x, const float* __restrict__ attr,
                const float* __restrict__ b1, const float* __restrict__ b2,
                const bf16_t* __restrict__ wf, float* __restrict__ out) {
    __shared__ bf16_t smid[2 * HALF_E];
    __shared__ float  sattr[32];
    __shared__ float  sb1[672];
    __shared__ float  sb2[128];

    const int tid   = threadIdx.x;
    const int lane  = tid & 63;
    const int w     = tid >> 6;
    const int wl    = w & 1;       // wave-in-half: 0/1
    const int half  = w >> 1;      // row half: 0/1
    const int rlane = lane & 15;
    const int q     = lane >> 4;
    const int rowbase = blockIdx.x * 32;
    const int rowh    = rowbase + half * 16;

    // ---------------- S0: stage 32 rows (de-interleaved bf16) -------------
#pragma unroll
    for (int it = 0; it < 15; ++it) {                  // 15*256 = 3840 exact
        int idx = tid + it * 256;
        int row = idx / 120;
        int c4  = idx - row * 120;
        const float4 v = ((const float4*)(x + (size_t)(rowbase + row) * 480))[c4];
        float vals[4] = {v.x, v.y, v.z, v.w};
        int sbase = (row >> 4) * HALF_E + (row & 15) * XDE_S;
        int base = c4 * 4;
#pragma unroll
        for (int e = 0; e < 4; ++e) {
            int col = base + e;
            int dc;
            if (col < 128) dc = col;
            else if (col < 320) { int r = col - 128; int m = r / 3; int i = r - m * 3; dc = 128 + i * 64 + m; }
            else                { int r = col - 320; int m = r / 5; int i = r - m * 5; dc = 320 + i * 32 + m; }
            smid[sbase + dc] = (bf16_t)vals[e];
        }
    }
    for (int i = tid; i < 672; i += 256) sb1[i] = b1[i];
    if (tid < 128) sb2[tid] = b2[tid];
    if (tid < 32)  sattr[tid] = attr[rowbase + tid];
    __syncthreads();                                   // B1

    bf16_t* sm = smid + half * HALF_E;

    // Issue S1's first three weight tiles immediately (depth-3 pipeline;
    // vmcnt work overlaps the LDS fragment extraction below).
    const bf16_t* base10 = wf + OFF_W10 + (lane << 3);
    bf16x8 bc[4], bn[4], b2f[4];
    {
        const bf16_t* p0 = base10 + ((wl * 4) << 9);
        const bf16_t* p1 = base10 + (((wl + 2) * 4) << 9);
        const bf16_t* p2 = base10 + (((wl + 4) * 4) << 9);
#pragma unroll
        for (int f = 0; f < 4; ++f) bc[f]  = *(const bf16x8*)(p0 + (f << 9));
#pragma unroll
        for (int f = 0; f < 4; ++f) bn[f]  = *(const bf16x8*)(p1 + (f << 9));
#pragma unroll
        for (int f = 0; f < 4; ++f) b2f[f] = *(const bf16x8*)(p2 + (f << 9));
    }

    // per-wave attr registers (row = rowh + q*4 + r)
    float sat[4];
#pragma unroll
    for (int r = 0; r < 4; ++r) sat[r] = sattr[half * 16 + q * 4 + r];

    // ---------------- extract A fragments (all up-front) ------------------
    bf16x8 a0[4], a1[3][2], a2[5];
    {
        int rb = rlane * XDE_S + q * 8;
#pragma unroll
        for (int f = 0; f < 4; ++f) a0[f] = *(const bf16x8*)&sm[rb + f * 32];
#pragma unroll
        for (int i = 0; i < 3; ++i)
#pragma unroll
            for (int f = 0; f < 2; ++f) a1[i][f] = *(const bf16x8*)&sm[rb + 128 + i * 64 + f * 32];
#pragma unroll
        for (int i = 0; i < 5; ++i) a2[i] = *(const bf16x8*)&sm[rb + 320 + i * 32];
    }

    // sigmoid gates in registers. gv[k] <- S1 iter 12+k (gate tile 24+wl+2k);
    // consumed by P1l1 (gv[0..5]) and P1l2 (gv[6..8]). Same wave, same lane.
    float gv[9][4];

    // ---------------- S1: P1l0, 21 iters, depth-3 pipeline ----------------
    {
        const float inv = 0.088388347648318447f;       // 1/sqrt(128)
#pragma unroll
        for (int ti = 0; ti < 21; ++ti) {
            int t = wl + ti * 2;
            bf16x8 bf_[4] = {b2f[0], b2f[1], b2f[2], b2f[3]};
            if (ti < 18) {                             // prefetch tile t+6
                const bf16_t* p = base10 + (((t + 6) * 4) << 9);
#pragma unroll
                for (int f = 0; f < 4; ++f) bf_[f] = *(const bf16x8*)(p + (f << 9));
            }
            f32x4 acc = {0.f, 0.f, 0.f, 0.f};
#pragma unroll
            for (int f = 0; f < 4; ++f) acc = mfma16(a0[f], bc[f], acc);
            int c = t * 16 + rlane;
            float bias = sb1[c];
            if (ti < 12) {                             // t<24: scalars -> silu -> mid0
#pragma unroll
                for (int r = 0; r < 4; ++r) {
                    float v = acc[r] * inv * sat[r] + bias;
                    float s = v * fast_rcp(1.f + __expf(-v));
                    sm[MID0_B + (q * 4 + r) * MID0_S + c] = (bf16_t)s;
                }
            } else {                                   // gates -> sigmoid -> regs
#pragma unroll
                for (int r = 0; r < 4; ++r) {
                    float v = acc[r] * inv * sat[r] + bias;
                    gv[ti - 12][r] = fast_rcp(1.f + __expf(-v));
                }
            }
#pragma unroll
            for (int f = 0; f < 4; ++f) { bc[f] = bn[f]; bn[f] = b2f[f]; b2f[f] = bf_[f]; }
        }
    }

    // Cross-barrier prefetch for S2: P1l1 tiles 0,1 (consumed first) and
    // P2l0 tile 0. All stay in flight across B2.
    bf16x8 pw11[2][2];
    bf16x8 pw20[2][12];
    {
        const bf16_t* pa = wf + OFF_W11 + ((wl * 2) << 9) + (lane << 3);
        pw11[0][0] = *(const bf16x8*)pa;
        pw11[0][1] = *(const bf16x8*)(pa + 512);
        const bf16_t* pb = wf + OFF_W11 + (((wl + 2) * 2) << 9) + (lane << 3);
        pw11[1][0] = *(const bf16x8*)pb;
        pw11[1][1] = *(const bf16x8*)(pb + 512);
        const bf16_t* p20 = wf + OFF_W20 + ((wl * 12) << 9) + (lane << 3);
#pragma unroll
        for (int f = 0; f < 12; ++f) pw20[0][f] = *(const bf16x8*)(p20 + (f << 9));
    }
    __syncthreads();                                   // B2

    // Issue P2l0 tile 1 loads now — they fly over the whole P1l1 phase.
    {
        const bf16_t* p20 = wf + OFF_W20 + (((wl + 2) * 12) << 9) + (lane << 3);
#pragma unroll
        for (int f = 0; f < 12; ++f) pw20[1][f] = *(const bf16x8*)(p20 + (f << 9));
    }

    // ---------------- S2a: P1l1 (6 tiles, depth-2 rolling) -> mid1 --------
    {
        const float inv = 0.125f;                      // 1/sqrt(64)
#pragma unroll
        for (int ti = 0; ti < 6; ++ti) {
            int t = wl + ti * 2;
            bf16x8 b0  = pw11[ti & 1][0];
            bf16x8 b1f = pw11[ti & 1][1];
            if (ti < 4) {                              // reload slot with tile ti+2
                const bf16_t* p = wf + OFF_W11 + (((wl + (ti + 2) * 2) * 2) << 9) + (lane << 3);
                pw11[ti & 1][0] = *(const bf16x8*)p;
                pw11[ti & 1][1] = *(const bf16x8*)(p + 512);
            }
            f32x4 acc[3];
#pragma unroll
            for (int i = 0; i < 3; ++i) {
                f32x4 a = {0.f, 0.f, 0.f, 0.f};
                a = mfma16(a1[i][0], b0, a);
                a = mfma16(a1[i][1], b1f, a);
                acc[i] = a;
            }
            int m = t * 16 + rlane;
#pragma unroll
            for (int r = 0; r < 4; ++r) {
                int row = q * 4 + r;
                float g = gv[ti][r] * inv * sat[r];
#pragma unroll
                for (int i = 0; i < 3; ++i)
                    sm[i * 3200 + row * MID1_S + m] = (bf16_t)(acc[i][r] * g);
            }
        }
    }

    // ---------------- S2b: P2l0 (out cols 0..127, 4 tiles, rolling) -------
    {
        const float inv = 0.051031036307982884f;       // 1/sqrt(384)
        bf16x8 am[12];
        int rb = MID0_B + rlane * MID0_S + q * 8;
#pragma unroll
        for (int f = 0; f < 12; ++f) am[f] = *(const bf16x8*)&sm[rb + f * 32];
#pragma unroll
        for (int ti = 0; ti < 4; ++ti) {
            int t = wl + ti * 2;
            bf16x8 cur[12];
#pragma unroll
            for (int f = 0; f < 12; ++f) cur[f] = pw20[ti & 1][f];
            if (ti < 2) {                              // reload slot with tile ti+2
                const bf16_t* p = wf + OFF_W20 + (((wl + (ti + 2) * 2) * 12) << 9) + (lane << 3);
#pragma unroll
                for (int f = 0; f < 12; ++f) pw20[ti & 1][f] = *(const bf16x8*)(p + (f << 9));
            }
            float bias = sb2[t * 16 + rlane];
            f32x4 acc = {0.f, 0.f, 0.f, 0.f};
#pragma unroll
            for (int f = 0; f < 12; ++f) acc = mfma16(am[f], cur[f], acc);
            int c = t * 16 + rlane;
#pragma unroll
            for (int r = 0; r < 4; ++r)
                out[(size_t)(rowh + q * 4 + r) * 480 + c] = acc[r] * inv * sat[r] + bias;
        }
    }

    // Cross-barrier prefetch for S3: ALL P1l2 weights (3 tiles) + P2l1
    // tile 0. In flight across B3.
    bf16x8 pv12[3], pv21[2][6];
    {
#pragma unroll
        for (int tj = 0; tj < 3; ++tj)
            pv12[tj] = *(const bf16x8*)(wf + OFF_W12 + ((wl + tj * 2) << 9) + (lane << 3));
        const bf16_t* p21 = wf + OFF_W21 + ((wl * 6) << 9) + (lane << 3);
#pragma unroll
        for (int f = 0; f < 6; ++f) pv21[0][f] = *(const bf16x8*)(p21 + (f << 9));
    }
    __syncthreads();                                   // B3

    // Issue P2l1 tile 1 loads now — hidden under P1l2.
    {
        const bf16_t* p21 = wf + OFF_W21 + (((wl + 2) * 6) << 9) + (lane << 3);
#pragma unroll
        for (int f = 0; f < 6; ++f) pv21[1][f] = *(const bf16x8*)(p21 + (f << 9));
    }

    // ---------------- S3a: P1l2 (mid2, 3 tiles, weights in regs) ----------
    {
        const float inv = 0.17677669529663689f;        // 1/sqrt(32)
#pragma unroll
        for (int tj = 0; tj < 3; ++tj) {
            int t = wl + tj * 2;
            f32x4 acc[5];
#pragma unroll
            for (int i = 0; i < 5; ++i) {
                f32x4 a = {0.f, 0.f, 0.f, 0.f};
                acc[i] = mfma16(a2[i], pv12[tj], a);
            }
            int m = t * 16 + rlane;
#pragma unroll
            for (int r = 0; r < 4; ++r) {
                int row = q * 4 + r;
                float g = gv[6 + tj][r] * inv * sat[r];
#pragma unroll
                for (int i = 0; i < 5; ++i)
                    sm[MID2_B + i * 1664 + row * MID2_S + m] = (bf16_t)(acc[i][r] * g);
            }
        }
    }

    // ---------------- S3b: P2l1 (out cols 128..319, 2 tiles) --------------
    {
        const float inv = 0.072168783648703220f;       // 1/sqrt(192)
        bf16x8 am21[3][6];
#pragma unroll
        for (int i = 0; i < 3; ++i) {
            int rb = i * 3200 + rlane * MID1_S + q * 8;
#pragma unroll
            for (int f = 0; f < 6; ++f) am21[i][f] = *(const bf16x8*)&sm[rb + f * 32];
        }
#pragma unroll
        for (int ti = 0; ti < 2; ++ti) {
            int t = wl + ti * 2;
            f32x4 acc[3];
#pragma unroll
            for (int i = 0; i < 3; ++i) {
                f32x4 a = {0.f, 0.f, 0.f, 0.f};
#pragma unroll
                for (int f = 0; f < 6; ++f) a = mfma16(am21[i][f], pv21[ti][f], a);
                acc[i] = a;
            }
            int o = t * 16 + rlane;
#pragma unroll
            for (int r = 0; r < 4; ++r) {
                float s = inv * sat[r];
                float* dst = out + (size_t)(rowh + q * 4 + r) * 480 + 128 + o * 3;
                dst[0] = acc[0][r] * s;
                dst[1] = acc[1][r] * s;
                dst[2] = acc[2][r] * s;
            }
        }
    }

    // Cross-barrier prefetch for S4 (both waves of each half: tile wl).
    bf16x8 pv22[3];
    {
        const bf16_t* p22 = wf + OFF_W22 + ((wl * 3) << 9) + (lane << 3);
#pragma unroll
        for (int f = 0; f < 3; ++f) pv22[f] = *(const bf16x8*)(p22 + (f << 9));
    }
    __syncthreads();                                   // B4

    // ---------------- S4: P2l2 (out cols 320..479, 1 tile/wave) ----------
    {
        const float inv = 0.10206207261596575f;        // 1/sqrt(96)
        int t = wl;
        f32x4 acc[5];
#pragma unroll
        for (int i = 0; i < 5; ++i) {
            bf16x8 am[3];
            int rb = MID2_B + i * 1664 + rlane * MID2_S + q * 8;
#pragma unroll
            for (int f = 0; f < 3; ++f) am[f] = *(const bf16x8*)&sm[rb + f * 32];
            f32x4 a = {0.f, 0.f, 0.f, 0.f};
#pragma unroll
            for (int f = 0; f < 3; ++f) a = mfma16(am[f], pv22[f], a);
            acc[i] = a;
        }
        int o = t * 16 + rlane;
#pragma unroll
        for (int r = 0; r < 4; ++r) {
            float s = inv * sat[r];
            float* dst = out + (size_t)(rowh + q * 4 + r) * 480 + 320 + o * 5;
#pragma unroll
            for (int i = 0; i < 5; ++i) dst[i] = acc[i][r] * s;
        }
    }
}

extern "C" void kernel_launch(void* const* d_in, const int* in_sizes, int n_in,
                              void* d_out, int out_size, void* d_ws, size_t ws_size,
                              hipStream_t stream) {
    const float* x    = (const float*)d_in[0];
    const float* attr = (const float*)d_in[1];
    const float* W10  = (const float*)d_in[2];
    const float* W11  = (const float*)d_in[3];
    const float* W12  = (const float*)d_in[4];
    const float* b1   = (const float*)d_in[5];
    const float* W20  = (const float*)d_in[6];
    const float* W21  = (const float*)d_in[7];
    const float* W22  = (const float*)d_in[8];
    const float* b2   = (const float*)d_in[9];
    float*  out = (float*)d_out;
    bf16_t* wf  = (bf16_t*)d_ws;

    int N = in_sizes[0] / 480;       // 100000

    prep_weights<<<dim3((W_TOTAL + 255) / 256), dim3(256), 0, stream>>>(
        W10, W11, W12, W20, W21, W22, wf);
    ffn_kernel<<<dim3(N / 32), dim3(256), 0, stream>>>(
        x, attr, b1, b2, wf, out);
}